// Round 5
// baseline (1133.213 us; speedup 1.0000x reference)
//
#include <hip/hip_runtime.h>
#include <stdint.h>

#define NROWS 32768
#define DDIM  512
#define KCODES 8192
#define CAP 128
#define MARGIN 5e-4f

// ws layout (bytes)
#define OFF_ZBF  0          // 32768*512*2 = 33554432
#define OFF_EBF  33554432   // 8192*512*2  = 8388608
#define OFF_RMIN 41943040   // 32768*4
#define OFF_CCNT 42074112   // 32768*4
#define OFF_CIDX 42205184   // 32768*128*4 = 16777216
#define OFF_LOSS 58982400   // 8

typedef __attribute__((ext_vector_type(4))) float floatx4;
typedef __attribute__((ext_vector_type(8))) __bf16 bf16x8;
typedef __attribute__((ext_vector_type(8))) unsigned short ushort8;

__device__ __forceinline__ unsigned fmap(float f) {
    unsigned u = __float_as_uint(f);
    return (u & 0x80000000u) ? ~u : (u | 0x80000000u);
}
__device__ __forceinline__ float funmap(unsigned u) {
    unsigned v = (u & 0x80000000u) ? (u & 0x7fffffffu) : ~u;
    return __uint_as_float(v);
}
__device__ __forceinline__ unsigned short f2bf(float f) {
    unsigned u = __float_as_uint(f);
    unsigned r = 0x7fffu + ((u >> 16) & 1u);
    return (unsigned short)((u + r) >> 16);
}

// ---- phase 0a: fp32 -> bf16 bits, 8 elems/thread ----
__global__ __launch_bounds__(256) void k_convert(const float* __restrict__ src,
                                                 unsigned short* __restrict__ dst, int n) {
    int i = (blockIdx.x * 256 + threadIdx.x) * 8;
    if (i >= n) return;
    floatx4 a = *(const floatx4*)(src + i);
    floatx4 b = *(const floatx4*)(src + i + 4);
    ushort8 o;
#pragma unroll
    for (int j = 0; j < 4; j++) { o[j] = f2bf(a[j]); o[j + 4] = f2bf(b[j]); }
    *(ushort8*)(dst + i) = o;
}

// ---- phase 0b: init accumulators ----
__global__ __launch_bounds__(256) void k_init(unsigned* __restrict__ rmin,
                                              unsigned* __restrict__ ccnt,
                                              double* __restrict__ loss) {
    int i = blockIdx.x * 256 + threadIdx.x;
    if (i < NROWS) { rmin[i] = 0xFFFFFFFFu; ccnt[i] = 0u; }
    if (i == 0) *loss = 0.0;
}

// ================= phase 1: 256x256 8-phase bf16 MFMA GEMM + argmin/candidates ========
// 512 threads = 8 waves (2M x 4N). BM=BN=256, BK=64. LDS: 2 dbuf x (A 256x64 + B 256x64)
// shorts, XOR-swizzled (write via pre-swizzled global source col, read with same XOR).
// Schedule (per iteration = K-tiles t,t+1; 8 phases): front-loaded ds_reads at ph1/ph5
// (lgkmcnt(0) forced before that phase's closing barrier => both buffer regions are free
// from the next phase on), 1 stage-unit (128 rows x 64 k = 2 gload16/thread) per phase,
// vmcnt(6) ONLY at ph4/ph8 (3 units in flight; proves next tile fully landed). setprio(1)
// around each 16-MFMA cluster (T5). Tail stages clamp to tile 7 (written, never read).
__global__ __launch_bounds__(512, 2) void k_gemm(const unsigned short* __restrict__ zb,
                                                 const unsigned short* __restrict__ eb,
                                                 unsigned* __restrict__ rowminU,
                                                 unsigned* __restrict__ candCnt,
                                                 unsigned* __restrict__ candIdx) {
    __shared__ unsigned short lds[65536];   // [A:2x16384][B:2x16384] shorts = 128 KiB
    __shared__ unsigned sMinU[256];
    __shared__ float sThr[256];

    const int t = threadIdx.x;
    const int w = t >> 6;                 // wave 0..7
    const int l = t & 63;
    const int wr = w >> 2, wc = w & 3;    // 2M x 4N wave grid; wave tile 128 x 64
    const int lr = l & 15, lg = l >> 4;
    const int rowT  = blockIdx.x * 256;   // 128 row tiles
    const int codeT = blockIdx.y * 256;   // 32 code tiles

    // staging per-thread geometry: unit = 128 rows x 64 k; 2 gload16/thread
    const int sr  = t >> 3;                       // 0..63 (row within half of unit)
    const int sc8 = t & 7;                        // 16B-granule
    const int scsw = ((sc8) ^ (sr & 7)) * 8;      // pre-swizzled source col (shorts)

    floatx4 acc[8][4];
#pragma unroll
    for (int m = 0; m < 8; m++)
#pragma unroll
        for (int n = 0; n < 4; n++) acc[m][n] = (floatx4){0.f, 0.f, 0.f, 0.f};

    bf16x8 afr[8][2];   // A frags: m 0..7, ks 0..1
    bf16x8 bfr[4][2];   // B frags: n 0..3, ks 0..1

#define STAGE(kt, unit, bsel)                                                          \
    do {                                                                               \
        const int _k0 = (kt) * 64;                                                     \
        const unsigned short* _src = ((unit) < 2) ? zb : eb;                           \
        const int _grow = (((unit) < 2) ? rowT : codeT) + ((unit) & 1) * 128 + sr;     \
        unsigned short* _dst = lds + (((unit) < 2) ? 0 : 32768) + (bsel) * 16384       \
                               + (((unit) & 1) * 128 + sr) * 64 + sc8 * 8;             \
        __builtin_amdgcn_global_load_lds(                                              \
            (const __attribute__((address_space(1))) unsigned int*)(_src + (size_t)_grow * DDIM + _k0 + scsw), \
            (__attribute__((address_space(3))) unsigned int*)_dst, 16, 0, 0);          \
        __builtin_amdgcn_global_load_lds(                                              \
            (const __attribute__((address_space(1))) unsigned int*)(_src + (size_t)(_grow + 64) * DDIM + _k0 + scsw), \
            (__attribute__((address_space(3))) unsigned int*)(_dst + 64 * 64), 16, 0, 0); \
    } while (0)

#define LOADFRAGS(bsel)                                                                \
    do {                                                                               \
        const unsigned short* _A = lds + (bsel) * 16384;                               \
        const unsigned short* _B = lds + 32768 + (bsel) * 16384;                       \
        _Pragma("unroll")                                                              \
        for (int _m = 0; _m < 8; _m++) {                                               \
            const int _row = wr * 128 + _m * 16 + lr;                                  \
            _Pragma("unroll")                                                          \
            for (int _ks = 0; _ks < 2; _ks++)                                          \
                afr[_m][_ks] = *(const bf16x8*)(_A + _row * 64 +                       \
                                (((_ks) * 32 + lg * 8) ^ ((lr & 7) << 3)));            \
        }                                                                              \
        _Pragma("unroll")                                                              \
        for (int _n = 0; _n < 4; _n++) {                                               \
            const int _row = wc * 64 + _n * 16 + lr;                                   \
            _Pragma("unroll")                                                          \
            for (int _ks = 0; _ks < 2; _ks++)                                          \
                bfr[_n][_ks] = *(const bf16x8*)(_B + _row * 64 +                       \
                                (((_ks) * 32 + lg * 8) ^ ((lr & 7) << 3)));            \
        }                                                                              \
    } while (0)

#define MFMAG(g)                                                                       \
    do {                                                                               \
        __builtin_amdgcn_s_setprio(1);                                                 \
        _Pragma("unroll")                                                              \
        for (int _mm = 0; _mm < 2; _mm++)                                              \
            _Pragma("unroll")                                                          \
            for (int _ks = 0; _ks < 2; _ks++)                                          \
                _Pragma("unroll")                                                      \
                for (int _n = 0; _n < 4; _n++)                                         \
                    acc[(g) * 2 + _mm][_n] = __builtin_amdgcn_mfma_f32_16x16x32_bf16(  \
                        afr[(g) * 2 + _mm][_ks], bfr[_n][_ks], acc[(g) * 2 + _mm][_n], 0, 0, 0); \
        __builtin_amdgcn_s_setprio(0);                                                 \
    } while (0)

#define BAR() __builtin_amdgcn_s_barrier()
#define LGKM0() do { asm volatile("s_waitcnt lgkmcnt(0)" ::: "memory"); \
                     __builtin_amdgcn_sched_barrier(0); } while (0)
#define VMC6() do { asm volatile("s_waitcnt vmcnt(6)" ::: "memory"); \
                    __builtin_amdgcn_sched_barrier(0); } while (0)
#define CLMP(x) ((x) < 7 ? (x) : 7)

    if (t < 256) sMinU[t] = 0xFFFFFFFFu;

    // prologue: tile0 all 4 units -> buf0; tile1 A0,A1,B0 -> buf1; wait tile0 landed
    STAGE(0, 0, 0); STAGE(0, 1, 0); STAGE(0, 2, 0); STAGE(0, 3, 0);
    STAGE(1, 0, 1); STAGE(1, 1, 1); STAGE(1, 2, 1);
    VMC6();
    BAR();

    for (int it = 0; it < 4; ++it) {
        const int kt = 2 * it;
        // ph1: read tile kt (buf0); stage (kt+1).B1 -> buf1
        LOADFRAGS(0);
        STAGE(CLMP(kt + 1), 3, 1);
        BAR(); LGKM0();
        MFMAG(0);
        BAR();
        // ph2
        STAGE(CLMP(kt + 2), 0, 0); BAR(); MFMAG(1); BAR();
        // ph3
        STAGE(CLMP(kt + 2), 1, 0); BAR(); MFMAG(2); BAR();
        // ph4
        STAGE(CLMP(kt + 2), 2, 0); VMC6(); BAR(); MFMAG(3); BAR();
        // ph5: read tile kt+1 (buf1); stage (kt+2).B1 -> buf0
        LOADFRAGS(1);
        STAGE(CLMP(kt + 2), 3, 0);
        BAR(); LGKM0();
        MFMAG(0);
        BAR();
        // ph6
        STAGE(CLMP(kt + 3), 0, 1); BAR(); MFMAG(1); BAR();
        // ph7
        STAGE(CLMP(kt + 3), 1, 1); BAR(); MFMAG(2); BAR();
        // ph8
        STAGE(CLMP(kt + 3), 2, 1); VMC6(); BAR(); MFMAG(3); BAR();
    }

    __syncthreads();   // full drain once before epilogue

    // ---- epilogue: per-row tile-min via shfl + LDS atomicMin ----
    // C/D layout: col = lane&15 (code), row = (lane>>4)*4 + j   [m89-verified]
#pragma unroll
    for (int m = 0; m < 8; m++) {
#pragma unroll
        for (int j = 0; j < 4; j++) {
            float v = fminf(fminf(-2.f * acc[m][0][j], -2.f * acc[m][1][j]),
                            fminf(-2.f * acc[m][2][j], -2.f * acc[m][3][j]));
#pragma unroll
            for (int s = 1; s < 16; s <<= 1) v = fminf(v, __shfl_xor(v, s, 64));
            if (lr == 0)
                atomicMin(&sMinU[wr * 128 + m * 16 + lg * 4 + j], fmap(v));
        }
    }
    __syncthreads();
    if (t < 256) {
        unsigned g = rowminU[rowT + t];              // stale-ok cross-block running min
        unsigned tm = sMinU[t];
        sThr[t] = funmap(tm < g ? tm : g) + MARGIN;  // superset-safe threshold
        atomicMin(&rowminU[rowT + t], tm);           // 1 global atomic per row per block
    }
    __syncthreads();

    // ---- candidate admission ----
#pragma unroll
    for (int m = 0; m < 8; m++) {
#pragma unroll
        for (int j = 0; j < 4; j++) {
            const int rl = wr * 128 + m * 16 + lg * 4 + j;
            const float thr = sThr[rl];
#pragma unroll
            for (int n = 0; n < 4; n++) {
                float d = -2.f * acc[m][n][j];
                if (d <= thr) {
                    unsigned pos = atomicAdd(&candCnt[rowT + rl], 1u);
                    if (pos < CAP)
                        candIdx[(size_t)(rowT + rl) * CAP + pos] =
                            (unsigned)(codeT + wc * 64 + n * 16 + lr);
                }
            }
        }
    }
#undef STAGE
#undef LOADFRAGS
#undef MFMAG
#undef BAR
#undef LGKM0
#undef VMC6
#undef CLMP
}

// ---- phase 2: exact rescore (one wave per row) + outputs ----
__global__ __launch_bounds__(256) void k_rescore(const float* __restrict__ z,
                                                 const float* __restrict__ emb,
                                                 const unsigned* __restrict__ candCnt,
                                                 const unsigned* __restrict__ candIdx,
                                                 float* __restrict__ out,
                                                 double* __restrict__ lossAcc) {
    const int w = threadIdx.x >> 6, l = threadIdx.x & 63;
    const int row = blockIdx.x * 4 + w;
    const float* zr = z + (size_t)row * DDIM;
    floatx4 za  = *(const floatx4*)(zr + l * 8);
    floatx4 zb4 = *(const floatx4*)(zr + l * 8 + 4);

    // s1 = ||x||^2 in f64, rounded once to f32 (uniform-shift invariant vs numpy)
    double s1 = 0.0;
#pragma unroll
    for (int j = 0; j < 4; j++) { s1 += (double)za[j] * za[j]; s1 += (double)zb4[j] * zb4[j]; }
#pragma unroll
    for (int s = 1; s < 64; s <<= 1) s1 += __shfl_xor(s1, s, 64);
    const float s1f = (float)s1;

    auto score = [&](unsigned c) -> unsigned long long {
        const float* er = emb + (size_t)c * DDIM;
        floatx4 ea  = *(const floatx4*)(er + l * 8);
        floatx4 eb4 = *(const floatx4*)(er + l * 8 + 4);
        double dt = 0.0;
#pragma unroll
        for (int j = 0; j < 4; j++) {
            dt += (double)za[j]  * (double)ea[j];
            dt += (double)zb4[j] * (double)eb4[j];
        }
#pragma unroll
        for (int s = 1; s < 64; s <<= 1) dt += __shfl_xor(dt, s, 64);
        float uf = (float)(2.0 * dt);       // matches fl32(2*M_k)
        float df = s1f - uf;                // matches fl32(s1 - 2M) (||e||^2 provably vanishes)
        return ((unsigned long long)fmap(df) << 32) | (unsigned long long)c;
    };

    unsigned cnt = candCnt[row];
    unsigned long long best = ~0ull;
    if (cnt <= CAP) {
        for (unsigned i = 0; i < cnt; i++) {
            unsigned long long k = score(candIdx[(size_t)row * CAP + i]);
            best = k < best ? k : best;
        }
    } else {  // overflow fallback: exact brute force (deterministic, rare)
        for (unsigned c = 0; c < KCODES; c++) {
            unsigned long long k = score(c);
            best = k < best ? k : best;
        }
    }
    const unsigned idx = (unsigned)best;  // low 32 bits

    // outputs: quantized_st = z + (q - z) in f32 (exact ST replication), loss partial
    const float* er = emb + (size_t)idx * DDIM + l * 8;
    float* oq = out + 1 + (size_t)row * DDIM + l * 8;   // 4B-aligned only
    double lp = 0.0;
#pragma unroll
    for (int j = 0; j < 8; j++) {
        float zv = (j < 4) ? za[j] : zb4[j - 4];
        float q  = er[j];
        oq[j] = zv + (q - zv);
        double d = (double)q - (double)zv;
        lp += d * d;
    }
#pragma unroll
    for (int s = 1; s < 64; s <<= 1) lp += __shfl_xor(lp, s, 64);
    if (l == 0) {
        out[1 + 16777216 + row] = (float)idx;   // indices as f32 values
        atomicAdd(lossAcc, lp);
    }
}

// ---- phase 3: finalize loss = 1.25 * mean ----
__global__ void k_final(const double* __restrict__ lossAcc, float* __restrict__ out) {
    if (threadIdx.x == 0 && blockIdx.x == 0)
        out[0] = (float)(1.25 * (*lossAcc) * (1.0 / 16777216.0));
}

extern "C" void kernel_launch(void* const* d_in, const int* in_sizes, int n_in,
                              void* d_out, int out_size, void* d_ws, size_t ws_size,
                              hipStream_t stream) {
    const float* z   = (const float*)d_in[0];
    const float* emb = (const float*)d_in[1];
    float* out = (float*)d_out;
    char* ws = (char*)d_ws;
    unsigned short* zbf = (unsigned short*)(ws + OFF_ZBF);
    unsigned short* ebf = (unsigned short*)(ws + OFF_EBF);
    unsigned* rmin = (unsigned*)(ws + OFF_RMIN);
    unsigned* ccnt = (unsigned*)(ws + OFF_CCNT);
    unsigned* cidx = (unsigned*)(ws + OFF_CIDX);
    double* loss = (double*)(ws + OFF_LOSS);

    k_convert<<<dim3(NROWS * DDIM / 2048), 256, 0, stream>>>(z, zbf, NROWS * DDIM);
    k_convert<<<dim3(KCODES * DDIM / 2048), 256, 0, stream>>>(emb, ebf, KCODES * DDIM);
    k_init<<<dim3(128), 256, 0, stream>>>(rmin, ccnt, loss);
    // grid.x = row tiles (fast-varying): consecutive blocks share the B(code) tile in L2,
    // and a row's 32 code-tiles are time-staggered => running min tightens admissions.
    k_gemm<<<dim3(128, 32), 512, 0, stream>>>(zbf, ebf, rmin, ccnt, cidx);
    k_rescore<<<dim3(NROWS / 4), 256, 0, stream>>>(z, emb, ccnt, cidx, out, loss);
    k_final<<<dim3(1), 64, 0, stream>>>(loss, out);
}

// Round 6
// 932.295 us; speedup vs baseline: 1.2155x; 1.2155x over previous
//
#include <hip/hip_runtime.h>
#include <stdint.h>

#define NROWS 32768
#define DDIM  512
#define KCODES 8192
#define CAP 128
#define MARGIN 5e-4f

// ws layout (bytes)
#define OFF_ZBF  0          // 32768*512*2 = 33554432
#define OFF_EBF  33554432   // 8192*512*2  = 8388608
#define OFF_RMIN 41943040   // 32768*4
#define OFF_CCNT 42074112   // 32768*4
#define OFF_CIDX 42205184   // 32768*128*4 = 16777216
#define OFF_LOSS 58982400   // 8

typedef __attribute__((ext_vector_type(4))) float floatx4;
typedef __attribute__((ext_vector_type(8))) __bf16 bf16x8;
typedef __attribute__((ext_vector_type(8))) unsigned short ushort8;

__device__ __forceinline__ unsigned fmap(float f) {
    unsigned u = __float_as_uint(f);
    return (u & 0x80000000u) ? ~u : (u | 0x80000000u);
}
__device__ __forceinline__ float funmap(unsigned u) {
    unsigned v = (u & 0x80000000u) ? (u & 0x7fffffffu) : ~u;
    return __uint_as_float(v);
}
__device__ __forceinline__ unsigned short f2bf(float f) {
    unsigned u = __float_as_uint(f);
    unsigned r = 0x7fffu + ((u >> 16) & 1u);
    return (unsigned short)((u + r) >> 16);
}

// ---- phase 0a: fp32 -> bf16 bits, 8 elems/thread ----
__global__ __launch_bounds__(256) void k_convert(const float* __restrict__ src,
                                                 unsigned short* __restrict__ dst, int n) {
    int i = (blockIdx.x * 256 + threadIdx.x) * 8;
    if (i >= n) return;
    floatx4 a = *(const floatx4*)(src + i);
    floatx4 b = *(const floatx4*)(src + i + 4);
    ushort8 o;
#pragma unroll
    for (int j = 0; j < 4; j++) { o[j] = f2bf(a[j]); o[j + 4] = f2bf(b[j]); }
    *(ushort8*)(dst + i) = o;
}

// ---- phase 0b: init accumulators ----
__global__ __launch_bounds__(256) void k_init(unsigned* __restrict__ rmin,
                                              unsigned* __restrict__ ccnt,
                                              double* __restrict__ loss) {
    int i = blockIdx.x * 256 + threadIdx.x;
    if (i < NROWS) { rmin[i] = 0xFFFFFFFFu; ccnt[i] = 0u; }
    if (i == 0) *loss = 0.0;
}

// ============ phase 1: 256x128 counted-vmcnt bf16 MFMA GEMM + argmin/candidates =======
// 512 threads = 8 waves (4M x 2N); wave tile 64x64 => acc 64 + afr 32 + bfr 32 regs
// (fits 256-unified at 2 waves/SIMD; round-5's 128x64 wave tile spilled: WRITE 481MB).
// LDS 96KB: 2dbuf x (A 256x64 + B 128x64) shorts, XOR-swizzled both-sides (rule #21).
// Per K-tile: ph1 front-loads ALL 16 frag ds_reads -> lgkmcnt(0) -> barrier (region
// provably free for ALL waves) -> stage t+2 units into this buffer; 6 stage units
// spread ph1(2)/ph2(1)/ph3(1)/ph4(2); vmcnt(6) ONLY at ph4 (leaves t+2's 6 in flight,
// proves t+1 landed); barrier; MFMA quads between stages. Loads never drain to 0 (T4).
__global__ __launch_bounds__(512, 2) void k_gemm(const unsigned short* __restrict__ zb,
                                                 const unsigned short* __restrict__ eb,
                                                 unsigned* __restrict__ rowminU,
                                                 unsigned* __restrict__ candCnt,
                                                 unsigned* __restrict__ candIdx) {
    __shared__ unsigned short lds[49152];   // A: [0,32768) 2x(256x64); B: [32768,49152) 2x(128x64)
    __shared__ unsigned sMinU[256];
    __shared__ float sThr[256];

    const int t = threadIdx.x;
    const int w = t >> 6;                 // wave 0..7
    const int l = t & 63;
    const int wr = w >> 1, wc = w & 1;    // 4M x 2N wave grid; wave tile 64 x 64
    const int lr = l & 15, lg = l >> 4;
    const int rowT  = blockIdx.x * 256;   // 128 row tiles
    const int codeT = blockIdx.y * 128;   // 64 code tiles

    // staging: unit = 64 rows x 64 k (8KB) = 1 gload16/thread. Units: 0..3 A, 4..5 B.
    const int sr  = t >> 3;                       // 0..63 row within unit
    const int sc8 = t & 7;                        // 16B granule
    const int scsw = (sc8 ^ (sr & 7)) * 8;        // pre-swizzled source col (shorts)

    floatx4 acc[4][4];
#pragma unroll
    for (int m = 0; m < 4; m++)
#pragma unroll
        for (int n = 0; n < 4; n++) acc[m][n] = (floatx4){0.f, 0.f, 0.f, 0.f};

    bf16x8 afr[4][2];   // A frags: m 0..3, ks 0..1
    bf16x8 bfr[4][2];   // B frags: n 0..3, ks 0..1

#define STAGE(kt, unit, bsel)                                                          \
    do {                                                                               \
        const unsigned short* _g = ((unit) < 4)                                        \
            ? zb + (size_t)(rowT  + (unit) * 64 + sr) * DDIM + (kt) * 64 + scsw        \
            : eb + (size_t)(codeT + ((unit) - 4) * 64 + sr) * DDIM + (kt) * 64 + scsw; \
        unsigned short* _d = ((unit) < 4)                                              \
            ? lds + (bsel) * 16384 + ((unit) * 64 + sr) * 64 + sc8 * 8                 \
            : lds + 32768 + (bsel) * 8192 + (((unit) - 4) * 64 + sr) * 64 + sc8 * 8;   \
        __builtin_amdgcn_global_load_lds(                                              \
            (const __attribute__((address_space(1))) unsigned int*)_g,                 \
            (__attribute__((address_space(3))) unsigned int*)_d, 16, 0, 0);            \
    } while (0)

#define LOADFRAGS(bsel)                                                                \
    do {                                                                               \
        const unsigned short* _A = lds + (bsel) * 16384;                               \
        const unsigned short* _B = lds + 32768 + (bsel) * 8192;                        \
        _Pragma("unroll")                                                              \
        for (int _m = 0; _m < 4; _m++) {                                               \
            const int _row = wr * 64 + _m * 16 + lr;                                   \
            _Pragma("unroll")                                                          \
            for (int _ks = 0; _ks < 2; _ks++)                                          \
                afr[_m][_ks] = *(const bf16x8*)(_A + _row * 64 +                       \
                                ((_ks * 32 + lg * 8) ^ ((lr & 7) << 3)));              \
        }                                                                              \
        _Pragma("unroll")                                                              \
        for (int _n = 0; _n < 4; _n++) {                                               \
            const int _row = wc * 64 + _n * 16 + lr;                                   \
            _Pragma("unroll")                                                          \
            for (int _ks = 0; _ks < 2; _ks++)                                          \
                bfr[_n][_ks] = *(const bf16x8*)(_B + _row * 64 +                       \
                                ((_ks * 32 + lg * 8) ^ ((lr & 7) << 3)));              \
        }                                                                              \
    } while (0)

#define MFMAG(g)                                                                       \
    do {                                                                               \
        __builtin_amdgcn_s_setprio(1);                                                 \
        _Pragma("unroll")                                                              \
        for (int _ks = 0; _ks < 2; _ks++)                                              \
            _Pragma("unroll")                                                          \
            for (int _n = 0; _n < 4; _n++)                                             \
                acc[(g)][_n] = __builtin_amdgcn_mfma_f32_16x16x32_bf16(                \
                    afr[(g)][_ks], bfr[_n][_ks], acc[(g)][_n], 0, 0, 0);               \
        __builtin_amdgcn_s_setprio(0);                                                 \
    } while (0)

#define BAR() __builtin_amdgcn_s_barrier()
#define LGKM0() do { asm volatile("s_waitcnt lgkmcnt(0)" ::: "memory"); \
                     __builtin_amdgcn_sched_barrier(0); } while (0)
#define VMC6() do { asm volatile("s_waitcnt vmcnt(6)" ::: "memory"); \
                    __builtin_amdgcn_sched_barrier(0); } while (0)
#define CLMP(x) ((x) < 7 ? (x) : 7)

    if (t < 256) sMinU[t] = 0xFFFFFFFFu;

    // prologue: tile0 -> buf0 (6 units), tile1 -> buf1 (6 units); wait tile0 landed (6 left)
    STAGE(0, 0, 0); STAGE(0, 1, 0); STAGE(0, 2, 0); STAGE(0, 3, 0); STAGE(0, 4, 0); STAGE(0, 5, 0);
    STAGE(1, 0, 1); STAGE(1, 1, 1); STAGE(1, 2, 1); STAGE(1, 3, 1); STAGE(1, 4, 1); STAGE(1, 5, 1);
    VMC6();
    BAR();

#pragma unroll 2
    for (int t0 = 0; t0 < 8; ++t0) {
        const int b  = t0 & 1;
        const int nk = CLMP(t0 + 2);
        // ph1: read ALL frags of tile t0 (buf b); all-waves drain; region b now free
        LOADFRAGS(b);
        LGKM0();
        BAR();
        STAGE(nk, 0, b); STAGE(nk, 1, b);
        MFMAG(0);
        // ph2
        STAGE(nk, 2, b); MFMAG(1);
        // ph3
        STAGE(nk, 3, b); MFMAG(2);
        // ph4: finish staging t0+2; vmcnt(6) => tile t0+1 fully landed; all waves sync
        STAGE(nk, 4, b); STAGE(nk, 5, b);
        VMC6();
        BAR();
        MFMAG(3);
    }

    __syncthreads();   // full drain (vmcnt/lgkm) before LDS reuse in epilogue

    // ---- epilogue: per-row tile-min via shfl + LDS atomicMin ----
    // C/D layout: col = lane&15 (code), row = (lane>>4)*4 + j   [m89-verified]
#pragma unroll
    for (int m = 0; m < 4; m++) {
#pragma unroll
        for (int j = 0; j < 4; j++) {
            float v = fminf(fminf(-2.f * acc[m][0][j], -2.f * acc[m][1][j]),
                            fminf(-2.f * acc[m][2][j], -2.f * acc[m][3][j]));
#pragma unroll
            for (int s = 1; s < 16; s <<= 1) v = fminf(v, __shfl_xor(v, s, 64));
            if (lr == 0)
                atomicMin(&sMinU[wr * 64 + m * 16 + lg * 4 + j], fmap(v));
        }
    }
    __syncthreads();
    if (t < 256) {
        unsigned g = rowminU[rowT + t];              // stale-ok cross-block running min
        unsigned tm = sMinU[t];
        sThr[t] = funmap(tm < g ? tm : g) + MARGIN;  // superset-safe threshold
        atomicMin(&rowminU[rowT + t], tm);           // 1 global atomic per row per block
    }
    __syncthreads();

    // ---- candidate admission ----
#pragma unroll
    for (int m = 0; m < 4; m++) {
#pragma unroll
        for (int j = 0; j < 4; j++) {
            const int rl = wr * 64 + m * 16 + lg * 4 + j;
            const float thr = sThr[rl];
#pragma unroll
            for (int n = 0; n < 4; n++) {
                float d = -2.f * acc[m][n][j];
                if (d <= thr) {
                    unsigned pos = atomicAdd(&candCnt[rowT + rl], 1u);
                    if (pos < CAP)
                        candIdx[(size_t)(rowT + rl) * CAP + pos] =
                            (unsigned)(codeT + wc * 64 + n * 16 + lr);
                }
            }
        }
    }
#undef STAGE
#undef LOADFRAGS
#undef MFMAG
#undef BAR
#undef LGKM0
#undef VMC6
#undef CLMP
}

// ---- phase 2: exact rescore (one wave per row) + outputs ----
__global__ __launch_bounds__(256) void k_rescore(const float* __restrict__ z,
                                                 const float* __restrict__ emb,
                                                 const unsigned* __restrict__ candCnt,
                                                 const unsigned* __restrict__ candIdx,
                                                 float* __restrict__ out,
                                                 double* __restrict__ lossAcc) {
    const int w = threadIdx.x >> 6, l = threadIdx.x & 63;
    const int row = blockIdx.x * 4 + w;
    const float* zr = z + (size_t)row * DDIM;
    floatx4 za  = *(const floatx4*)(zr + l * 8);
    floatx4 zb4 = *(const floatx4*)(zr + l * 8 + 4);

    // s1 = ||x||^2 in f64, rounded once to f32 (uniform-shift invariant vs numpy)
    double s1 = 0.0;
#pragma unroll
    for (int j = 0; j < 4; j++) { s1 += (double)za[j] * za[j]; s1 += (double)zb4[j] * zb4[j]; }
#pragma unroll
    for (int s = 1; s < 64; s <<= 1) s1 += __shfl_xor(s1, s, 64);
    const float s1f = (float)s1;

    auto score = [&](unsigned c) -> unsigned long long {
        const float* er = emb + (size_t)c * DDIM;
        floatx4 ea  = *(const floatx4*)(er + l * 8);
        floatx4 eb4 = *(const floatx4*)(er + l * 8 + 4);
        double dt = 0.0;
#pragma unroll
        for (int j = 0; j < 4; j++) {
            dt += (double)za[j]  * (double)ea[j];
            dt += (double)zb4[j] * (double)eb4[j];
        }
#pragma unroll
        for (int s = 1; s < 64; s <<= 1) dt += __shfl_xor(dt, s, 64);
        float uf = (float)(2.0 * dt);       // matches fl32(2*M_k)
        float df = s1f - uf;                // matches fl32(s1 - 2M) (||e||^2 provably vanishes)
        return ((unsigned long long)fmap(df) << 32) | (unsigned long long)c;
    };

    unsigned cnt = candCnt[row];
    unsigned long long best = ~0ull;
    if (cnt <= CAP) {
        for (unsigned i = 0; i < cnt; i++) {
            unsigned long long k = score(candIdx[(size_t)row * CAP + i]);
            best = k < best ? k : best;
        }
    } else {  // overflow fallback: exact brute force (deterministic, rare)
        for (unsigned c = 0; c < KCODES; c++) {
            unsigned long long k = score(c);
            best = k < best ? k : best;
        }
    }
    const unsigned idx = (unsigned)best;  // low 32 bits

    // outputs: quantized_st = z + (q - z) in f32 (exact ST replication), loss partial
    const float* er = emb + (size_t)idx * DDIM + l * 8;
    float* oq = out + 1 + (size_t)row * DDIM + l * 8;   // 4B-aligned only
    double lp = 0.0;
#pragma unroll
    for (int j = 0; j < 8; j++) {
        float zv = (j < 4) ? za[j] : zb4[j - 4];
        float q  = er[j];
        oq[j] = zv + (q - zv);
        double d = (double)q - (double)zv;
        lp += d * d;
    }
#pragma unroll
    for (int s = 1; s < 64; s <<= 1) lp += __shfl_xor(lp, s, 64);
    if (l == 0) {
        out[1 + 16777216 + row] = (float)idx;   // indices as f32 values
        atomicAdd(lossAcc, lp);
    }
}

// ---- phase 3: finalize loss = 1.25 * mean ----
__global__ void k_final(const double* __restrict__ lossAcc, float* __restrict__ out) {
    if (threadIdx.x == 0 && blockIdx.x == 0)
        out[0] = (float)(1.25 * (*lossAcc) * (1.0 / 16777216.0));
}

extern "C" void kernel_launch(void* const* d_in, const int* in_sizes, int n_in,
                              void* d_out, int out_size, void* d_ws, size_t ws_size,
                              hipStream_t stream) {
    const float* z   = (const float*)d_in[0];
    const float* emb = (const float*)d_in[1];
    float* out = (float*)d_out;
    char* ws = (char*)d_ws;
    unsigned short* zbf = (unsigned short*)(ws + OFF_ZBF);
    unsigned short* ebf = (unsigned short*)(ws + OFF_EBF);
    unsigned* rmin = (unsigned*)(ws + OFF_RMIN);
    unsigned* ccnt = (unsigned*)(ws + OFF_CCNT);
    unsigned* cidx = (unsigned*)(ws + OFF_CIDX);
    double* loss = (double*)(ws + OFF_LOSS);

    k_convert<<<dim3(NROWS * DDIM / 2048), 256, 0, stream>>>(z, zbf, NROWS * DDIM);
    k_convert<<<dim3(KCODES * DDIM / 2048), 256, 0, stream>>>(emb, ebf, KCODES * DDIM);
    k_init<<<dim3(128), 256, 0, stream>>>(rmin, ccnt, loss);
    // grid.x = row tiles (fast-varying): consecutive blocks share the B(code) tile in L2,
    // and a row's code-tiles are time-staggered => running min tightens admissions.
    k_gemm<<<dim3(128, 64), 512, 0, stream>>>(zbf, ebf, rmin, ccnt, cidx);
    k_rescore<<<dim3(NROWS / 4), 256, 0, stream>>>(z, emb, ccnt, cidx, out, loss);
    k_final<<<dim3(1), 64, 0, stream>>>(loss, out);
}

// Round 7
// 825.311 us; speedup vs baseline: 1.3731x; 1.1296x over previous
//
#include <hip/hip_runtime.h>
#include <stdint.h>

#define NROWS 32768
#define DDIM  512
#define KCODES 8192
#define CAP 128
#define MARGIN 5e-4f

// ws layout (bytes)
#define OFF_ZBF  0          // 32768*512*2 = 33554432
#define OFF_EBF  33554432   // 8192*512*2  = 8388608
#define OFF_RMIN 41943040   // 32768*4
#define OFF_CCNT 42074112   // 32768*4
#define OFF_CIDX 42205184   // 32768*128*4 = 16777216
#define OFF_LOSS 58982400   // 8

typedef __attribute__((ext_vector_type(4))) float floatx4;
typedef __attribute__((ext_vector_type(8))) __bf16 bf16x8;
typedef __attribute__((ext_vector_type(8))) unsigned short ushort8;

__device__ __forceinline__ unsigned fmap(float f) {
    unsigned u = __float_as_uint(f);
    return (u & 0x80000000u) ? ~u : (u | 0x80000000u);
}
__device__ __forceinline__ float funmap(unsigned u) {
    unsigned v = (u & 0x80000000u) ? (u & 0x7fffffffu) : ~u;
    return __uint_as_float(v);
}
__device__ __forceinline__ unsigned short f2bf(float f) {
    unsigned u = __float_as_uint(f);
    unsigned r = 0x7fffu + ((u >> 16) & 1u);
    return (unsigned short)((u + r) >> 16);
}

// ---- phase 0a: fp32 -> bf16 bits, 8 elems/thread ----
__global__ __launch_bounds__(256) void k_convert(const float* __restrict__ src,
                                                 unsigned short* __restrict__ dst, int n) {
    int i = (blockIdx.x * 256 + threadIdx.x) * 8;
    if (i >= n) return;
    floatx4 a = *(const floatx4*)(src + i);
    floatx4 b = *(const floatx4*)(src + i + 4);
    ushort8 o;
#pragma unroll
    for (int j = 0; j < 4; j++) { o[j] = f2bf(a[j]); o[j + 4] = f2bf(b[j]); }
    *(ushort8*)(dst + i) = o;
}

// ---- phase 0b: init accumulators ----
__global__ __launch_bounds__(256) void k_init(unsigned* __restrict__ rmin,
                                              unsigned* __restrict__ ccnt,
                                              double* __restrict__ loss) {
    int i = blockIdx.x * 256 + threadIdx.x;
    if (i < NROWS) { rmin[i] = 0xFFFFFFFFu; ccnt[i] = 0u; }
    if (i == 0) *loss = 0.0;
}

// ========== phase 1: 256x256 counted-vmcnt bf16 MFMA GEMM + argmin/candidates =========
// 512 threads = 8 waves (4M x 2N); wave tile 64x128: acc 2x[4][4]=128 (AGPR) + afr 32
// + bfr 32 (time-shared between the two n-halves) => ~230 regs, fits 256 @2 waves/SIMD.
// LDS 128KB: 2dbuf x (A 256x64 + B 256x64) shorts, XOR-swizzled both-sides (rule #21).
// Per K-tile t (buf b): ph1 reads A-frags + B-low frags (16 ds_read) -> lgkm0 -> BAR
//   => regions {A all, B rows 0-63 & 128-191} read by ALL waves => stage 6 units of
//   tile t+2 there; MFMA half 0 (32).
// ph2 reads B-high frags (8) -> lgkm0 -> BAR => rows {64-127,192-255} free => stage
//   last 2 units; MFMA half 1 (32); vmcnt(8) (own stages of t+2 in flight, all of
//   t+1 landed) -> BAR (all waves' t+1 stages landed) -> next tile. Never vmcnt(0). T4.
__global__ __launch_bounds__(512, 2) void k_gemm(const unsigned short* __restrict__ zb,
                                                 const unsigned short* __restrict__ eb,
                                                 unsigned* __restrict__ rowminU,
                                                 unsigned* __restrict__ candCnt,
                                                 unsigned* __restrict__ candIdx) {
    __shared__ unsigned short lds[65536];   // A: [0,32768) 2x(256x64); B: [32768,65536)
    __shared__ unsigned sMinU[256];
    __shared__ float sThr[256];

    const int t = threadIdx.x;
    const int w = t >> 6;                 // wave 0..7
    const int l = t & 63;
    const int wr = w >> 1, wc = w & 1;    // 4M x 2N; wave tile 64 rows x 128 codes
    const int lr = l & 15, lg = l >> 4;
    const int rowT  = blockIdx.x * 256;   // 128 row tiles
    const int codeT = blockIdx.y * 256;   // 32 code tiles

    // staging: unit = 64 rows x 64 k (8KB) = 1 gload16/thread. Units 0..3 A, 4..7 B.
    const int sr  = t >> 3;                       // 0..63 row within unit
    const int sc8 = t & 7;                        // 16B granule
    const int scsw = (sc8 ^ (sr & 7)) * 8;        // pre-swizzled source col (shorts)

    floatx4 acc0[4][4], acc1[4][4];               // n-half 0 / 1
#pragma unroll
    for (int m = 0; m < 4; m++)
#pragma unroll
        for (int n = 0; n < 4; n++) {
            acc0[m][n] = (floatx4){0.f, 0.f, 0.f, 0.f};
            acc1[m][n] = (floatx4){0.f, 0.f, 0.f, 0.f};
        }

    bf16x8 afr[4][2];   // A frags: m 0..3, ks 0..1 (persistent per K-tile)
    bf16x8 bfr[4][2];   // B frags: nn 0..3, ks 0..1 (reused: half0 then half1)

#define STAGE(kt, unit, bsel)                                                          \
    do {                                                                               \
        const unsigned short* _g = ((unit) < 4)                                        \
            ? zb + (size_t)(rowT  + (unit) * 64 + sr) * DDIM + (kt) * 64 + scsw        \
            : eb + (size_t)(codeT + ((unit) - 4) * 64 + sr) * DDIM + (kt) * 64 + scsw; \
        unsigned short* _d = ((unit) < 4)                                              \
            ? lds + (bsel) * 16384 + ((unit) * 64 + sr) * 64 + sc8 * 8                 \
            : lds + 32768 + (bsel) * 16384 + (((unit) - 4) * 64 + sr) * 64 + sc8 * 8;  \
        __builtin_amdgcn_global_load_lds(                                              \
            (const __attribute__((address_space(1))) unsigned int*)_g,                 \
            (__attribute__((address_space(3))) unsigned int*)_d, 16, 0, 0);            \
    } while (0)

#define LDA(bsel)                                                                      \
    do {                                                                               \
        const unsigned short* _A = lds + (bsel) * 16384;                               \
        _Pragma("unroll")                                                              \
        for (int _m = 0; _m < 4; _m++) {                                               \
            const int _row = wr * 64 + _m * 16 + lr;                                   \
            _Pragma("unroll")                                                          \
            for (int _ks = 0; _ks < 2; _ks++)                                          \
                afr[_m][_ks] = *(const bf16x8*)(_A + _row * 64 +                       \
                                ((_ks * 32 + lg * 8) ^ ((lr & 7) << 3)));              \
        }                                                                              \
    } while (0)

#define LDB(bsel, h)                                                                   \
    do {                                                                               \
        const unsigned short* _B = lds + 32768 + (bsel) * 16384;                       \
        _Pragma("unroll")                                                              \
        for (int _nn = 0; _nn < 4; _nn++) {                                            \
            const int _row = wc * 128 + (h) * 64 + _nn * 16 + lr;                      \
            _Pragma("unroll")                                                          \
            for (int _ks = 0; _ks < 2; _ks++)                                          \
                bfr[_nn][_ks] = *(const bf16x8*)(_B + _row * 64 +                      \
                                ((_ks * 32 + lg * 8) ^ ((lr & 7) << 3)));              \
        }                                                                              \
    } while (0)

#define MFMAH(accH)                                                                    \
    do {                                                                               \
        __builtin_amdgcn_s_setprio(1);                                                 \
        _Pragma("unroll")                                                              \
        for (int _m = 0; _m < 4; _m++)                                                 \
            _Pragma("unroll")                                                          \
            for (int _ks = 0; _ks < 2; _ks++)                                          \
                _Pragma("unroll")                                                      \
                for (int _nn = 0; _nn < 4; _nn++)                                      \
                    accH[_m][_nn] = __builtin_amdgcn_mfma_f32_16x16x32_bf16(           \
                        afr[_m][_ks], bfr[_nn][_ks], accH[_m][_nn], 0, 0, 0);          \
        __builtin_amdgcn_s_setprio(0);                                                 \
    } while (0)

#define BAR() __builtin_amdgcn_s_barrier()
#define LGKM0() do { asm volatile("s_waitcnt lgkmcnt(0)" ::: "memory"); \
                     __builtin_amdgcn_sched_barrier(0); } while (0)
#define VMC8() do { asm volatile("s_waitcnt vmcnt(8)" ::: "memory"); \
                    __builtin_amdgcn_sched_barrier(0); } while (0)
#define CLMP(x) ((x) < 7 ? (x) : 7)

    if (t < 256) sMinU[t] = 0xFFFFFFFFu;

    // prologue: tile0 -> buf0 (8 units), tile1 -> buf1 (8 units); wait tile0 (8 left)
    STAGE(0, 0, 0); STAGE(0, 1, 0); STAGE(0, 2, 0); STAGE(0, 3, 0);
    STAGE(0, 4, 0); STAGE(0, 5, 0); STAGE(0, 6, 0); STAGE(0, 7, 0);
    STAGE(1, 0, 1); STAGE(1, 1, 1); STAGE(1, 2, 1); STAGE(1, 3, 1);
    STAGE(1, 4, 1); STAGE(1, 5, 1); STAGE(1, 6, 1); STAGE(1, 7, 1);
    VMC8();
    BAR();

#pragma unroll 2
    for (int t0 = 0; t0 < 8; ++t0) {
        const int b  = t0 & 1;
        const int nk = CLMP(t0 + 2);
        // ph1: frags A(all) + B-low of tile t0; collective-complete; stage 6 units
        LDA(b);
        LDB(b, 0);          // B rows: wc0 -> 0..63 (unit 4), wc1 -> 128..191 (unit 6)
        LGKM0();
        BAR();
        STAGE(nk, 0, b); STAGE(nk, 1, b); STAGE(nk, 2, b); STAGE(nk, 3, b);
        STAGE(nk, 4, b); STAGE(nk, 6, b);
        MFMAH(acc0);
        // ph2: frags B-high; collective-complete; stage last 2; MFMA; t0+1 landed; sync
        LDB(b, 1);          // B rows: wc0 -> 64..127 (unit 5), wc1 -> 192..255 (unit 7)
        LGKM0();
        BAR();
        STAGE(nk, 5, b); STAGE(nk, 7, b);
        MFMAH(acc1);
        VMC8();
        BAR();
    }

    __syncthreads();   // dangling tail stages only touch ldsA/B, not sMinU/sThr

    // ---- epilogue: per-row tile-min via shfl + LDS atomicMin ----
    // C/D layout: col = lane&15 (code), row = (lane>>4)*4 + j   [m89-verified]
#pragma unroll
    for (int m = 0; m < 4; m++) {
#pragma unroll
        for (int j = 0; j < 4; j++) {
            float v = fminf(
                fminf(fminf(-2.f * acc0[m][0][j], -2.f * acc0[m][1][j]),
                      fminf(-2.f * acc0[m][2][j], -2.f * acc0[m][3][j])),
                fminf(fminf(-2.f * acc1[m][0][j], -2.f * acc1[m][1][j]),
                      fminf(-2.f * acc1[m][2][j], -2.f * acc1[m][3][j])));
#pragma unroll
            for (int s = 1; s < 16; s <<= 1) v = fminf(v, __shfl_xor(v, s, 64));
            if (lr == 0)
                atomicMin(&sMinU[wr * 64 + m * 16 + lg * 4 + j], fmap(v));
        }
    }
    __syncthreads();
    if (t < 256) {
        unsigned g = rowminU[rowT + t];              // stale-ok cross-block running min
        unsigned tm = sMinU[t];
        sThr[t] = funmap(tm < g ? tm : g) + MARGIN;  // superset-safe threshold
        atomicMin(&rowminU[rowT + t], tm);           // 1 global atomic per row per block
    }
    __syncthreads();

    // ---- candidate admission ----
#pragma unroll
    for (int m = 0; m < 4; m++) {
#pragma unroll
        for (int j = 0; j < 4; j++) {
            const int rl = wr * 64 + m * 16 + lg * 4 + j;
            const float thr = sThr[rl];
#pragma unroll
            for (int h = 0; h < 2; h++) {
#pragma unroll
                for (int nn = 0; nn < 4; nn++) {
                    float d = -2.f * (h ? acc1[m][nn][j] : acc0[m][nn][j]);
                    if (d <= thr) {
                        unsigned pos = atomicAdd(&candCnt[rowT + rl], 1u);
                        if (pos < CAP)
                            candIdx[(size_t)(rowT + rl) * CAP + pos] =
                                (unsigned)(codeT + wc * 128 + h * 64 + nn * 16 + lr);
                    }
                }
            }
        }
    }
#undef STAGE
#undef LDA
#undef LDB
#undef MFMAH
#undef BAR
#undef LGKM0
#undef VMC8
#undef CLMP
}

// ---- phase 2: exact rescore (one wave per row; 8 lane-groups score 8 cands in parallel)
__global__ __launch_bounds__(256) void k_rescore(const float* __restrict__ z,
                                                 const float* __restrict__ emb,
                                                 const unsigned* __restrict__ candCnt,
                                                 const unsigned* __restrict__ candIdx,
                                                 float* __restrict__ out,
                                                 double* __restrict__ lossAcc) {
    const int w = threadIdx.x >> 6, l = threadIdx.x & 63;
    const int row = blockIdx.x * 4 + w;
    const int g = l >> 3, q = l & 7;     // 8 groups x 8 lanes
    const float* zr = z + (size_t)row * DDIM;

    // old-layout chunk (dims l*8..+7) for s1 (bit-identical to prior rounds) + epilogue
    floatx4 za  = *(const floatx4*)(zr + l * 8);
    floatx4 zb4 = *(const floatx4*)(zr + l * 8 + 4);
    double s1 = 0.0;
#pragma unroll
    for (int j = 0; j < 4; j++) { s1 += (double)za[j] * za[j]; s1 += (double)zb4[j] * zb4[j]; }
#pragma unroll
    for (int s = 1; s < 64; s <<= 1) s1 += __shfl_xor(s1, s, 64);
    const float s1f = (float)s1;

    // scoring layout: lane owns dims q*64..+63 (same for all groups)
    floatx4 zq[16];
#pragma unroll
    for (int k = 0; k < 16; k++) zq[k] = *(const floatx4*)(zr + q * 64 + k * 4);

    auto score = [&](unsigned c) -> unsigned long long {
        const float* er = emb + (size_t)c * DDIM + q * 64;
        double dt = 0.0;
#pragma unroll
        for (int k = 0; k < 16; k++) {
            floatx4 e = *(const floatx4*)(er + k * 4);
            dt += (double)zq[k][0] * (double)e[0];
            dt += (double)zq[k][1] * (double)e[1];
            dt += (double)zq[k][2] * (double)e[2];
            dt += (double)zq[k][3] * (double)e[3];
        }
        dt += __shfl_xor(dt, 1, 64);      // 3-level reduce within 8-lane group
        dt += __shfl_xor(dt, 2, 64);
        dt += __shfl_xor(dt, 4, 64);
        float uf = (float)(2.0 * dt);     // matches fl32(2*M_k) (f64 dot exact to >>f32)
        float df = s1f - uf;              // matches fl32(s1 - 2M) (||e||^2 provably vanishes)
        return ((unsigned long long)fmap(df) << 32) | (unsigned long long)c;
    };

    unsigned cnt = candCnt[row];
    unsigned long long best = ~0ull;
    if (cnt <= CAP) {
        for (unsigned i = g; i < cnt; i += 8) {
            unsigned long long k = score(candIdx[(size_t)row * CAP + i]);
            best = k < best ? k : best;
        }
    } else {  // overflow fallback: exact brute force (deterministic, rare)
        for (unsigned c = g; c < KCODES; c += 8) {
            unsigned long long k = score(c);
            best = k < best ? k : best;
        }
    }
    // cross-group min of (ordered-df, idx) keys -> wave-wide reference argmin
#pragma unroll
    for (int s = 8; s < 64; s <<= 1) {
        unsigned long long o = __shfl_xor(best, s, 64);
        best = o < best ? o : best;
    }
    const unsigned idx = (unsigned)best;  // low 32 bits

    // outputs: quantized_st = z + (q - z) in f32 (exact ST replication), loss partial
    const float* er = emb + (size_t)idx * DDIM + l * 8;
    float* oq = out + 1 + (size_t)row * DDIM + l * 8;   // 4B-aligned only
    double lp = 0.0;
#pragma unroll
    for (int j = 0; j < 8; j++) {
        float zv = (j < 4) ? za[j] : zb4[j - 4];
        float qv = er[j];
        oq[j] = zv + (qv - zv);
        double d = (double)qv - (double)zv;
        lp += d * d;
    }
#pragma unroll
    for (int s = 1; s < 64; s <<= 1) lp += __shfl_xor(lp, s, 64);
    if (l == 0) {
        out[1 + 16777216 + row] = (float)idx;   // indices as f32 values
        atomicAdd(lossAcc, lp);
    }
}

// ---- phase 3: finalize loss = 1.25 * mean ----
__global__ void k_final(const double* __restrict__ lossAcc, float* __restrict__ out) {
    if (threadIdx.x == 0 && blockIdx.x == 0)
        out[0] = (float)(1.25 * (*lossAcc) * (1.0 / 16777216.0));
}

extern "C" void kernel_launch(void* const* d_in, const int* in_sizes, int n_in,
                              void* d_out, int out_size, void* d_ws, size_t ws_size,
                              hipStream_t stream) {
    const float* z   = (const float*)d_in[0];
    const float* emb = (const float*)d_in[1];
    float* out = (float*)d_out;
    char* ws = (char*)d_ws;
    unsigned short* zbf = (unsigned short*)(ws + OFF_ZBF);
    unsigned short* ebf = (unsigned short*)(ws + OFF_EBF);
    unsigned* rmin = (unsigned*)(ws + OFF_RMIN);
    unsigned* ccnt = (unsigned*)(ws + OFF_CCNT);
    unsigned* cidx = (unsigned*)(ws + OFF_CIDX);
    double* loss = (double*)(ws + OFF_LOSS);

    k_convert<<<dim3(NROWS * DDIM / 2048), 256, 0, stream>>>(z, zbf, NROWS * DDIM);
    k_convert<<<dim3(KCODES * DDIM / 2048), 256, 0, stream>>>(emb, ebf, KCODES * DDIM);
    k_init<<<dim3(128), 256, 0, stream>>>(rmin, ccnt, loss);
    // grid.x = row tiles (fast-varying): consecutive blocks share the B(code) tile in L2,
    // and a row's code-tiles are time-staggered => running min tightens admissions.
    k_gemm<<<dim3(128, 32), 512, 0, stream>>>(zbf, ebf, rmin, ccnt, cidx);
    k_rescore<<<dim3(NROWS / 4), 256, 0, stream>>>(z, emb, ccnt, cidx, out, loss);
    k_final<<<dim3(1), 64, 0, stream>>>(loss, out);
}

// Round 8
// 629.527 us; speedup vs baseline: 1.8001x; 1.3110x over previous
//
#include <hip/hip_runtime.h>
#include <stdint.h>

#define NROWS 32768
#define DDIM  512
#define KCODES 8192
#define CAP 128
#define MARGIN 5e-4f

// ws layout (bytes)
#define OFF_ZBF  0          // 32768*512*2 = 33554432
#define OFF_EBF  33554432   // 8192*512*2  = 8388608
#define OFF_RMIN 41943040   // 32768*4
#define OFF_CCNT 42074112   // 32768*4
#define OFF_CIDX 42205184   // 32768*128*4 = 16777216
#define OFF_LOSS 58982400   // 8

typedef __attribute__((ext_vector_type(4))) float floatx4;
typedef __attribute__((ext_vector_type(8))) __bf16 bf16x8;
typedef __attribute__((ext_vector_type(8))) unsigned short ushort8;

__device__ __forceinline__ unsigned fmap(float f) {
    unsigned u = __float_as_uint(f);
    return (u & 0x80000000u) ? ~u : (u | 0x80000000u);
}
__device__ __forceinline__ float funmap(unsigned u) {
    unsigned v = (u & 0x80000000u) ? (u & 0x7fffffffu) : ~u;
    return __uint_as_float(v);
}
__device__ __forceinline__ unsigned short f2bf(float f) {
    unsigned u = __float_as_uint(f);
    unsigned r = 0x7fffu + ((u >> 16) & 1u);
    return (unsigned short)((u + r) >> 16);
}

// ---- phase 0a: fp32 -> bf16 bits, 8 elems/thread ----
__global__ __launch_bounds__(256) void k_convert(const float* __restrict__ src,
                                                 unsigned short* __restrict__ dst, int n) {
    int i = (blockIdx.x * 256 + threadIdx.x) * 8;
    if (i >= n) return;
    floatx4 a = *(const floatx4*)(src + i);
    floatx4 b = *(const floatx4*)(src + i + 4);
    ushort8 o;
#pragma unroll
    for (int j = 0; j < 4; j++) { o[j] = f2bf(a[j]); o[j + 4] = f2bf(b[j]); }
    *(ushort8*)(dst + i) = o;
}

// ---- phase 0b: init accumulators ----
__global__ __launch_bounds__(256) void k_init(unsigned* __restrict__ rmin,
                                              unsigned* __restrict__ ccnt,
                                              double* __restrict__ loss) {
    int i = blockIdx.x * 256 + threadIdx.x;
    if (i < NROWS) { rmin[i] = 0xFFFFFFFFu; ccnt[i] = 0u; }
    if (i == 0) *loss = 0.0;
}

// ====== phase 1: 256x256 m201-style 4-phase/K-tile bf16 MFMA GEMM + argmin/cands ======
// 512 threads = 8 waves (2M x 4N); wave tile 128 rows x 64 codes. BK=64, 8 K-tiles.
// LDS 128KB: A 2x(256x64) + B 2x(256x64) shorts, XOR-swizzled both-sides (rule #21).
// Per K-tile t (buf b=t&1), 4 phases; phase q computes quadrant m=q*2,q*2+1 (16 MFMA):
//   ph0: ds_read B all (8) + A q0 (4); stage A1,A3(t+1)->buf b^1  [freed at t-1 end]
//   ph1: ds_read A q1 (4);             stage B0,B1(t+2)->buf b    [B freed after ph0 bar]
//   ph2: ds_read A q2 (4);             stage B2,B3(t+2)->buf b
//   ph3: ds_read A q3 (4);             stage A0,A2(t+2)->buf b    [rows 0-63/128-191
//        freed after ph1 bar]; then vmcnt(6)+BAR once per tile: leaves ph1-3's 6 in
//        flight, proves everything tile t+1 needs has landed. Never drains to 0 (T4).
// Each phase: reads+stages -> BAR -> lgkmcnt(0)+schedbar -> setprio(1) 16 MFMA -> BAR.
__global__ __launch_bounds__(512, 2) void k_gemm(const unsigned short* __restrict__ zb,
                                                 const unsigned short* __restrict__ eb,
                                                 unsigned* __restrict__ rowminU,
                                                 unsigned* __restrict__ candCnt,
                                                 unsigned* __restrict__ candIdx) {
    __shared__ unsigned short lds[65536];   // A: [0,32768) 2x(256x64); B: [32768,65536)
    __shared__ unsigned sMinU[256];
    __shared__ float sThr[256];

    const int t = threadIdx.x;
    const int w = t >> 6;                 // wave 0..7
    const int l = t & 63;
    const int wr = w >> 2, wc = w & 3;    // 2M x 4N; wave tile 128 rows x 64 codes
    const int lr = l & 15, lg = l >> 4;
    const int rowT  = blockIdx.x * 256;   // 128 row tiles
    const int codeT = blockIdx.y * 256;   // 32 code tiles

    // staging: unit = 64 rows x 64 k (8KB) = 1 gload16/thread. Units 0..3 A, 4..7 B.
    const int sr  = t >> 3;                       // 0..63 row within unit
    const int sc8 = t & 7;                        // 16B granule
    const int scsw = (sc8 ^ (sr & 7)) * 8;        // pre-swizzled source col (shorts)

    floatx4 acc[8][4];
#pragma unroll
    for (int m = 0; m < 8; m++)
#pragma unroll
        for (int n = 0; n < 4; n++) acc[m][n] = (floatx4){0.f, 0.f, 0.f, 0.f};

    bf16x8 afr[2][2];   // A frags for current quadrant (transient per phase)
    bf16x8 bfr[4][2];   // B frags persistent per K-tile

#define STAGE(kt, unit, bsel)                                                          \
    do {                                                                               \
        const unsigned short* _g = ((unit) < 4)                                        \
            ? zb + (size_t)(rowT  + (unit) * 64 + sr) * DDIM + (kt) * 64 + scsw        \
            : eb + (size_t)(codeT + ((unit) - 4) * 64 + sr) * DDIM + (kt) * 64 + scsw; \
        unsigned short* _d = ((unit) < 4)                                              \
            ? lds + (bsel) * 16384 + ((unit) * 64 + sr) * 64 + sc8 * 8                 \
            : lds + 32768 + (bsel) * 16384 + (((unit) - 4) * 64 + sr) * 64 + sc8 * 8;  \
        __builtin_amdgcn_global_load_lds(                                              \
            (const __attribute__((address_space(1))) unsigned int*)_g,                 \
            (__attribute__((address_space(3))) unsigned int*)_d, 16, 0, 0);            \
    } while (0)

#define LDB_ALL(bsel)                                                                  \
    do {                                                                               \
        const unsigned short* _B = lds + 32768 + (bsel) * 16384;                       \
        _Pragma("unroll")                                                              \
        for (int _nn = 0; _nn < 4; _nn++) {                                            \
            const int _row = wc * 64 + _nn * 16 + lr;                                  \
            _Pragma("unroll")                                                          \
            for (int _ks = 0; _ks < 2; _ks++)                                          \
                bfr[_nn][_ks] = *(const bf16x8*)(_B + _row * 64 +                      \
                                ((_ks * 32 + lg * 8) ^ ((lr & 7) << 3)));              \
        }                                                                              \
    } while (0)

#define LDA_Q(bsel, q)                                                                 \
    do {                                                                               \
        const unsigned short* _A = lds + (bsel) * 16384;                               \
        _Pragma("unroll")                                                              \
        for (int _mm = 0; _mm < 2; _mm++) {                                            \
            const int _row = wr * 128 + (q) * 32 + _mm * 16 + lr;                      \
            _Pragma("unroll")                                                          \
            for (int _ks = 0; _ks < 2; _ks++)                                          \
                afr[_mm][_ks] = *(const bf16x8*)(_A + _row * 64 +                      \
                                ((_ks * 32 + lg * 8) ^ ((lr & 7) << 3)));              \
        }                                                                              \
    } while (0)

#define MFMAQ(q)                                                                       \
    do {                                                                               \
        __builtin_amdgcn_s_setprio(1);                                                 \
        _Pragma("unroll")                                                              \
        for (int _mm = 0; _mm < 2; _mm++)                                              \
            _Pragma("unroll")                                                          \
            for (int _ks = 0; _ks < 2; _ks++)                                          \
                _Pragma("unroll")                                                      \
                for (int _nn = 0; _nn < 4; _nn++)                                      \
                    acc[(q) * 2 + _mm][_nn] = __builtin_amdgcn_mfma_f32_16x16x32_bf16( \
                        afr[_mm][_ks], bfr[_nn][_ks], acc[(q) * 2 + _mm][_nn], 0, 0, 0); \
        __builtin_amdgcn_s_setprio(0);                                                 \
    } while (0)

#define BAR() __builtin_amdgcn_s_barrier()
#define LGKM0() do { asm volatile("s_waitcnt lgkmcnt(0)" ::: "memory"); \
                     __builtin_amdgcn_sched_barrier(0); } while (0)
#define VMC6() do { asm volatile("s_waitcnt vmcnt(6)" ::: "memory"); \
                    __builtin_amdgcn_sched_barrier(0); } while (0)
#define CLMP(x) ((x) < 7 ? (x) : 7)

    if (t < 256) sMinU[t] = 0xFFFFFFFFu;

    // prologue: tile0 full (B0-3,A0,A2,A1,A3) -> buf0; tile1's B0-3,A0,A2 -> buf1.
    // vmcnt(6) leaves tile1's 6 in flight, tile0's 8 landed.
    STAGE(0, 4, 0); STAGE(0, 5, 0); STAGE(0, 6, 0); STAGE(0, 7, 0);
    STAGE(0, 0, 0); STAGE(0, 2, 0); STAGE(0, 1, 0); STAGE(0, 3, 0);
    STAGE(1, 4, 1); STAGE(1, 5, 1); STAGE(1, 6, 1); STAGE(1, 7, 1);
    STAGE(1, 0, 1); STAGE(1, 2, 1);
    VMC6();
    BAR();

#pragma unroll 2
    for (int t0 = 0; t0 < 8; ++t0) {
        const int b = t0 & 1;
        // ph0: B all + A q0; stage A1,A3(t+1) -> other buffer (freed since t-1 end)
        LDB_ALL(b);
        LDA_Q(b, 0);
        STAGE(CLMP(t0 + 1), 1, b ^ 1); STAGE(CLMP(t0 + 1), 3, b ^ 1);
        BAR(); LGKM0();
        MFMAQ(0);
        BAR();
        // ph1: A q1; stage B0,B1(t+2) -> buf b (B freed after ph0 bar)
        LDA_Q(b, 1);
        STAGE(CLMP(t0 + 2), 4, b); STAGE(CLMP(t0 + 2), 5, b);
        BAR(); LGKM0();
        MFMAQ(1);
        BAR();
        // ph2: A q2; stage B2,B3(t+2)
        LDA_Q(b, 2);
        STAGE(CLMP(t0 + 2), 6, b); STAGE(CLMP(t0 + 2), 7, b);
        BAR(); LGKM0();
        MFMAQ(2);
        BAR();
        // ph3: A q3; stage A0,A2(t+2) (rows 0-63/128-191 freed after ph1 bar)
        LDA_Q(b, 3);
        STAGE(CLMP(t0 + 2), 0, b); STAGE(CLMP(t0 + 2), 2, b);
        BAR(); LGKM0();
        MFMAQ(3);
        VMC6();
        BAR();
    }

    __syncthreads();   // dangling tail DMAs only touch lds[], not sMinU/sThr

    // ---- epilogue: per-row tile-min via shfl + LDS atomicMin ----
    // C/D layout: col = lane&15 (code), row = (lane>>4)*4 + j   [m89-verified]
#pragma unroll
    for (int m = 0; m < 8; m++) {
#pragma unroll
        for (int j = 0; j < 4; j++) {
            float v = fminf(fminf(-2.f * acc[m][0][j], -2.f * acc[m][1][j]),
                            fminf(-2.f * acc[m][2][j], -2.f * acc[m][3][j]));
#pragma unroll
            for (int s = 1; s < 16; s <<= 1) v = fminf(v, __shfl_xor(v, s, 64));
            if (lr == 0)
                atomicMin(&sMinU[wr * 128 + m * 16 + lg * 4 + j], fmap(v));
        }
    }
    __syncthreads();
    if (t < 256) {
        unsigned g = rowminU[rowT + t];              // stale-ok cross-block running min
        unsigned tm = sMinU[t];
        sThr[t] = funmap(tm < g ? tm : g) + MARGIN;  // superset-safe threshold
        atomicMin(&rowminU[rowT + t], tm);           // 1 global atomic per row per block
    }
    __syncthreads();

    // ---- candidate admission ----
#pragma unroll
    for (int m = 0; m < 8; m++) {
#pragma unroll
        for (int j = 0; j < 4; j++) {
            const int rl = wr * 128 + m * 16 + lg * 4 + j;
            const float thr = sThr[rl];
#pragma unroll
            for (int nn = 0; nn < 4; nn++) {
                float d = -2.f * acc[m][nn][j];
                if (d <= thr) {
                    unsigned pos = atomicAdd(&candCnt[rowT + rl], 1u);
                    if (pos < CAP)
                        candIdx[(size_t)(rowT + rl) * CAP + pos] =
                            (unsigned)(codeT + wc * 64 + nn * 16 + lr);
                }
            }
        }
    }
#undef STAGE
#undef LDB_ALL
#undef LDA_Q
#undef MFMAQ
#undef BAR
#undef LGKM0
#undef VMC6
#undef CLMP
}

// ---- phase 2: exact rescore (one wave per row; 8 lane-groups score 8 cands in parallel)
// Per-row f64 loss partial is written into the row's OWN candIdx slot (first 8 bytes)
// AFTER all candidate reads -- no cross-block hazard; k_lossred reduces with 64 atomics
// (replaces 32768 serialized f64 atomics to one address == the old ~400us residual).
__global__ __launch_bounds__(256) void k_rescore(const float* __restrict__ z,
                                                 const float* __restrict__ emb,
                                                 const unsigned* __restrict__ candCnt,
                                                 unsigned* __restrict__ candIdx,
                                                 float* __restrict__ out) {
    const int w = threadIdx.x >> 6, l = threadIdx.x & 63;
    const int row = blockIdx.x * 4 + w;
    const int g = l >> 3, q = l & 7;     // 8 groups x 8 lanes
    const float* zr = z + (size_t)row * DDIM;

    // old-layout chunk (dims l*8..+7) for s1 (bit-identical to prior rounds) + epilogue
    floatx4 za  = *(const floatx4*)(zr + l * 8);
    floatx4 zb4 = *(const floatx4*)(zr + l * 8 + 4);
    double s1 = 0.0;
#pragma unroll
    for (int j = 0; j < 4; j++) { s1 += (double)za[j] * za[j]; s1 += (double)zb4[j] * zb4[j]; }
#pragma unroll
    for (int s = 1; s < 64; s <<= 1) s1 += __shfl_xor(s1, s, 64);
    const float s1f = (float)s1;

    // scoring layout: lane owns dims q*64..+63 (same for all groups)
    floatx4 zq[16];
#pragma unroll
    for (int k = 0; k < 16; k++) zq[k] = *(const floatx4*)(zr + q * 64 + k * 4);

    auto score = [&](unsigned c) -> unsigned long long {
        const float* er = emb + (size_t)c * DDIM + q * 64;
        double dt = 0.0;
#pragma unroll
        for (int k = 0; k < 16; k++) {
            floatx4 e = *(const floatx4*)(er + k * 4);
            dt += (double)zq[k][0] * (double)e[0];
            dt += (double)zq[k][1] * (double)e[1];
            dt += (double)zq[k][2] * (double)e[2];
            dt += (double)zq[k][3] * (double)e[3];
        }
        dt += __shfl_xor(dt, 1, 64);      // 3-level reduce within 8-lane group
        dt += __shfl_xor(dt, 2, 64);
        dt += __shfl_xor(dt, 4, 64);
        float uf = (float)(2.0 * dt);     // matches fl32(2*M_k) (f64 dot exact to >>f32)
        float df = s1f - uf;              // matches fl32(s1 - 2M) (||e||^2 provably vanishes)
        return ((unsigned long long)fmap(df) << 32) | (unsigned long long)c;
    };

    unsigned cnt = candCnt[row];
    unsigned long long best = ~0ull;
    if (cnt <= CAP) {
        for (unsigned i = g; i < cnt; i += 8) {
            unsigned long long k = score(candIdx[(size_t)row * CAP + i]);
            best = k < best ? k : best;
        }
    } else {  // overflow fallback: exact brute force (deterministic, rare)
        for (unsigned c = g; c < KCODES; c += 8) {
            unsigned long long k = score(c);
            best = k < best ? k : best;
        }
    }
    // cross-group min of (ordered-df, idx) keys -> wave-wide reference argmin
#pragma unroll
    for (int s = 8; s < 64; s <<= 1) {
        unsigned long long o = __shfl_xor(best, s, 64);
        best = o < best ? o : best;
    }
    const unsigned idx = (unsigned)best;  // low 32 bits

    // outputs: quantized_st = z + (q - z) in f32 (exact ST replication), loss partial
    const float* er = emb + (size_t)idx * DDIM + l * 8;
    float* oq = out + 1 + (size_t)row * DDIM + l * 8;   // 4B-aligned only
    double lp = 0.0;
#pragma unroll
    for (int j = 0; j < 8; j++) {
        float zv = (j < 4) ? za[j] : zb4[j - 4];
        float qv = er[j];
        oq[j] = zv + (qv - zv);
        double d = (double)qv - (double)zv;
        lp += d * d;
    }
#pragma unroll
    for (int s = 1; s < 64; s <<= 1) lp += __shfl_xor(lp, s, 64);
    if (l == 0) {
        out[1 + 16777216 + row] = (float)idx;   // indices as f32 values
        // all candidate reads for this row happened above (wave-lockstep) -> safe
        ((double*)(candIdx + (size_t)row * CAP))[0] = lp;
    }
}

// ---- phase 2b: tree-reduce per-row losses (64 blocks, 64 atomics total) ----
__global__ __launch_bounds__(256) void k_lossred(const unsigned* __restrict__ candIdx,
                                                 double* __restrict__ lossAcc) {
    const int tid = blockIdx.x * 256 + threadIdx.x;   // 0..16383
    double s = ((const double*)(candIdx + (size_t)tid * CAP))[0]
             + ((const double*)(candIdx + (size_t)(tid + 16384) * CAP))[0];
#pragma unroll
    for (int sh = 1; sh < 64; sh <<= 1) s += __shfl_xor(s, sh, 64);
    __shared__ double partial[4];
    const int l = threadIdx.x & 63, w = threadIdx.x >> 6;
    if (l == 0) partial[w] = s;
    __syncthreads();
    if (threadIdx.x == 0)
        atomicAdd(lossAcc, partial[0] + partial[1] + partial[2] + partial[3]);
}

// ---- phase 3: finalize loss = 1.25 * mean ----
__global__ void k_final(const double* __restrict__ lossAcc, float* __restrict__ out) {
    if (threadIdx.x == 0 && blockIdx.x == 0)
        out[0] = (float)(1.25 * (*lossAcc) * (1.0 / 16777216.0));
}

extern "C" void kernel_launch(void* const* d_in, const int* in_sizes, int n_in,
                              void* d_out, int out_size, void* d_ws, size_t ws_size,
                              hipStream_t stream) {
    const float* z   = (const float*)d_in[0];
    const float* emb = (const float*)d_in[1];
    float* out = (float*)d_out;
    char* ws = (char*)d_ws;
    unsigned short* zbf = (unsigned short*)(ws + OFF_ZBF);
    unsigned short* ebf = (unsigned short*)(ws + OFF_EBF);
    unsigned* rmin = (unsigned*)(ws + OFF_RMIN);
    unsigned* ccnt = (unsigned*)(ws + OFF_CCNT);
    unsigned* cidx = (unsigned*)(ws + OFF_CIDX);
    double* loss = (double*)(ws + OFF_LOSS);

    k_convert<<<dim3(NROWS * DDIM / 2048), 256, 0, stream>>>(z, zbf, NROWS * DDIM);
    k_convert<<<dim3(KCODES * DDIM / 2048), 256, 0, stream>>>(emb, ebf, KCODES * DDIM);
    k_init<<<dim3(128), 256, 0, stream>>>(rmin, ccnt, loss);
    // grid.x = row tiles (fast-varying): consecutive blocks share the B(code) tile in L2,
    // and a row's code-tiles are time-staggered => running min tightens admissions.
    k_gemm<<<dim3(128, 32), 512, 0, stream>>>(zbf, ebf, rmin, ccnt, cidx);
    k_rescore<<<dim3(NROWS / 4), 256, 0, stream>>>(z, emb, ccnt, cidx, out);
    k_lossred<<<dim3(64), 256, 0, stream>>>(cidx, loss);
    k_final<<<dim3(1), 64, 0, stream>>>(loss, out);
}

// Round 9
// 569.635 us; speedup vs baseline: 1.9894x; 1.1051x over previous
//
#include <hip/hip_runtime.h>
#include <stdint.h>

#define NROWS 32768
#define DDIM  512
#define KCODES 8192
#define CAP 128
#define MARGIN 5e-4f

// ws layout (bytes)
#define OFF_ZBF  0          // 32768*512*2 = 33554432
#define OFF_EBF  33554432   // 8192*512*2  = 8388608
#define OFF_RMIN 41943040   // 32768*4
#define OFF_CCNT 42074112   // 32768*4
#define OFF_CIDX 42205184   // 32768*128*4 = 16777216
#define OFF_LOSS 58982400   // 8

typedef __attribute__((ext_vector_type(4))) float floatx4;
typedef __attribute__((ext_vector_type(8))) __bf16 bf16x8;
typedef __attribute__((ext_vector_type(8))) unsigned short ushort8;

__device__ __forceinline__ unsigned fmap(float f) {
    unsigned u = __float_as_uint(f);
    return (u & 0x80000000u) ? ~u : (u | 0x80000000u);
}
__device__ __forceinline__ float funmap(unsigned u) {
    unsigned v = (u & 0x80000000u) ? (u & 0x7fffffffu) : ~u;
    return __uint_as_float(v);
}
__device__ __forceinline__ unsigned short f2bf(float f) {
    unsigned u = __float_as_uint(f);
    unsigned r = 0x7fffu + ((u >> 16) & 1u);
    return (unsigned short)((u + r) >> 16);
}

// ---- phase 0a: fp32 -> bf16 bits, 8 elems/thread ----
__global__ __launch_bounds__(256) void k_convert(const float* __restrict__ src,
                                                 unsigned short* __restrict__ dst, int n) {
    int i = (blockIdx.x * 256 + threadIdx.x) * 8;
    if (i >= n) return;
    floatx4 a = *(const floatx4*)(src + i);
    floatx4 b = *(const floatx4*)(src + i + 4);
    ushort8 o;
#pragma unroll
    for (int j = 0; j < 4; j++) { o[j] = f2bf(a[j]); o[j + 4] = f2bf(b[j]); }
    *(ushort8*)(dst + i) = o;
}

// ---- phase 0b: init accumulators ----
__global__ __launch_bounds__(256) void k_init(unsigned* __restrict__ rmin,
                                              unsigned* __restrict__ ccnt,
                                              double* __restrict__ loss) {
    int i = blockIdx.x * 256 + threadIdx.x;
    if (i < NROWS) { rmin[i] = 0xFFFFFFFFu; ccnt[i] = 0u; }
    if (i == 0) *loss = 0.0;
}

// ========== phase 1: 256x256 counted-vmcnt bf16 MFMA GEMM + argmin/candidates =========
// [round-7 kernel, measured 427us / MfmaUtil 27.9% / 0 bank conflicts / no spill]
// 512 threads = 8 waves (4M x 2N); wave tile 64x128: acc 2x[4][4]=128 (AGPR) + afr 32
// + bfr 32 (time-shared between the two n-halves) => ~230 regs, fits 256 @2 waves/SIMD.
// LDS 128KB: 2dbuf x (A 256x64 + B 256x64) shorts, XOR-swizzled both-sides (rule #21).
// Per K-tile t (buf b): ph1 reads A-frags + B-low frags (16 ds_read) -> lgkm0 -> BAR
//   => regions {A all, B rows 0-63 & 128-191} read by ALL waves => stage 6 units of
//   tile t+2 there; MFMA half 0 (32).
// ph2 reads B-high frags (8) -> lgkm0 -> BAR => rows {64-127,192-255} free => stage
//   last 2 units; MFMA half 1 (32); vmcnt(8) (own stages of t+2 in flight, all of
//   t+1 landed) -> BAR (all waves' t+1 stages landed) -> next tile. Never vmcnt(0). T4.
__global__ __launch_bounds__(512, 2) void k_gemm(const unsigned short* __restrict__ zb,
                                                 const unsigned short* __restrict__ eb,
                                                 unsigned* __restrict__ rowminU,
                                                 unsigned* __restrict__ candCnt,
                                                 unsigned* __restrict__ candIdx) {
    __shared__ unsigned short lds[65536];   // A: [0,32768) 2x(256x64); B: [32768,65536)
    __shared__ unsigned sMinU[256];
    __shared__ float sThr[256];

    const int t = threadIdx.x;
    const int w = t >> 6;                 // wave 0..7
    const int l = t & 63;
    const int wr = w >> 1, wc = w & 1;    // 4M x 2N; wave tile 64 rows x 128 codes
    const int lr = l & 15, lg = l >> 4;
    const int rowT  = blockIdx.x * 256;   // 128 row tiles
    const int codeT = blockIdx.y * 256;   // 32 code tiles

    // staging: unit = 64 rows x 64 k (8KB) = 1 gload16/thread. Units 0..3 A, 4..7 B.
    const int sr  = t >> 3;                       // 0..63 row within unit
    const int sc8 = t & 7;                        // 16B granule
    const int scsw = (sc8 ^ (sr & 7)) * 8;        // pre-swizzled source col (shorts)

    floatx4 acc0[4][4], acc1[4][4];               // n-half 0 / 1
#pragma unroll
    for (int m = 0; m < 4; m++)
#pragma unroll
        for (int n = 0; n < 4; n++) {
            acc0[m][n] = (floatx4){0.f, 0.f, 0.f, 0.f};
            acc1[m][n] = (floatx4){0.f, 0.f, 0.f, 0.f};
        }

    bf16x8 afr[4][2];   // A frags: m 0..3, ks 0..1 (persistent per K-tile)
    bf16x8 bfr[4][2];   // B frags: nn 0..3, ks 0..1 (reused: half0 then half1)

#define STAGE(kt, unit, bsel)                                                          \
    do {                                                                               \
        const unsigned short* _g = ((unit) < 4)                                        \
            ? zb + (size_t)(rowT  + (unit) * 64 + sr) * DDIM + (kt) * 64 + scsw        \
            : eb + (size_t)(codeT + ((unit) - 4) * 64 + sr) * DDIM + (kt) * 64 + scsw; \
        unsigned short* _d = ((unit) < 4)                                              \
            ? lds + (bsel) * 16384 + ((unit) * 64 + sr) * 64 + sc8 * 8                 \
            : lds + 32768 + (bsel) * 16384 + (((unit) - 4) * 64 + sr) * 64 + sc8 * 8;  \
        __builtin_amdgcn_global_load_lds(                                              \
            (const __attribute__((address_space(1))) unsigned int*)_g,                 \
            (__attribute__((address_space(3))) unsigned int*)_d, 16, 0, 0);            \
    } while (0)

#define LDA(bsel)                                                                      \
    do {                                                                               \
        const unsigned short* _A = lds + (bsel) * 16384;                               \
        _Pragma("unroll")                                                              \
        for (int _m = 0; _m < 4; _m++) {                                               \
            const int _row = wr * 64 + _m * 16 + lr;                                   \
            _Pragma("unroll")                                                          \
            for (int _ks = 0; _ks < 2; _ks++)                                          \
                afr[_m][_ks] = *(const bf16x8*)(_A + _row * 64 +                       \
                                ((_ks * 32 + lg * 8) ^ ((lr & 7) << 3)));              \
        }                                                                              \
    } while (0)

#define LDB(bsel, h)                                                                   \
    do {                                                                               \
        const unsigned short* _B = lds + 32768 + (bsel) * 16384;                       \
        _Pragma("unroll")                                                              \
        for (int _nn = 0; _nn < 4; _nn++) {                                            \
            const int _row = wc * 128 + (h) * 64 + _nn * 16 + lr;                      \
            _Pragma("unroll")                                                          \
            for (int _ks = 0; _ks < 2; _ks++)                                          \
                bfr[_nn][_ks] = *(const bf16x8*)(_B + _row * 64 +                      \
                                ((_ks * 32 + lg * 8) ^ ((lr & 7) << 3)));              \
        }                                                                              \
    } while (0)

#define MFMAH(accH)                                                                    \
    do {                                                                               \
        __builtin_amdgcn_s_setprio(1);                                                 \
        _Pragma("unroll")                                                              \
        for (int _m = 0; _m < 4; _m++)                                                 \
            _Pragma("unroll")                                                          \
            for (int _ks = 0; _ks < 2; _ks++)                                          \
                _Pragma("unroll")                                                      \
                for (int _nn = 0; _nn < 4; _nn++)                                      \
                    accH[_m][_nn] = __builtin_amdgcn_mfma_f32_16x16x32_bf16(           \
                        afr[_m][_ks], bfr[_nn][_ks], accH[_m][_nn], 0, 0, 0);          \
        __builtin_amdgcn_s_setprio(0);                                                 \
    } while (0)

#define BAR() __builtin_amdgcn_s_barrier()
#define LGKM0() do { asm volatile("s_waitcnt lgkmcnt(0)" ::: "memory"); \
                     __builtin_amdgcn_sched_barrier(0); } while (0)
#define VMC8() do { asm volatile("s_waitcnt vmcnt(8)" ::: "memory"); \
                    __builtin_amdgcn_sched_barrier(0); } while (0)
#define CLMP(x) ((x) < 7 ? (x) : 7)

    if (t < 256) sMinU[t] = 0xFFFFFFFFu;

    // prologue: tile0 -> buf0 (8 units), tile1 -> buf1 (8 units); wait tile0 (8 left)
    STAGE(0, 0, 0); STAGE(0, 1, 0); STAGE(0, 2, 0); STAGE(0, 3, 0);
    STAGE(0, 4, 0); STAGE(0, 5, 0); STAGE(0, 6, 0); STAGE(0, 7, 0);
    STAGE(1, 0, 1); STAGE(1, 1, 1); STAGE(1, 2, 1); STAGE(1, 3, 1);
    STAGE(1, 4, 1); STAGE(1, 5, 1); STAGE(1, 6, 1); STAGE(1, 7, 1);
    VMC8();
    BAR();

#pragma unroll 2
    for (int t0 = 0; t0 < 8; ++t0) {
        const int b  = t0 & 1;
        const int nk = CLMP(t0 + 2);
        // ph1: frags A(all) + B-low of tile t0; collective-complete; stage 6 units
        LDA(b);
        LDB(b, 0);          // B rows: wc0 -> 0..63 (unit 4), wc1 -> 128..191 (unit 6)
        LGKM0();
        BAR();
        STAGE(nk, 0, b); STAGE(nk, 1, b); STAGE(nk, 2, b); STAGE(nk, 3, b);
        STAGE(nk, 4, b); STAGE(nk, 6, b);
        MFMAH(acc0);
        // ph2: frags B-high; collective-complete; stage last 2; MFMA; t0+1 landed; sync
        LDB(b, 1);          // B rows: wc0 -> 64..127 (unit 5), wc1 -> 192..255 (unit 7)
        LGKM0();
        BAR();
        STAGE(nk, 5, b); STAGE(nk, 7, b);
        MFMAH(acc1);
        VMC8();
        BAR();
    }

    __syncthreads();   // dangling tail stages only touch ldsA/B, not sMinU/sThr

    // ---- epilogue: per-row tile-min via shfl + LDS atomicMin ----
    // C/D layout: col = lane&15 (code), row = (lane>>4)*4 + j   [m89-verified]
#pragma unroll
    for (int m = 0; m < 4; m++) {
#pragma unroll
        for (int j = 0; j < 4; j++) {
            float v = fminf(
                fminf(fminf(-2.f * acc0[m][0][j], -2.f * acc0[m][1][j]),
                      fminf(-2.f * acc0[m][2][j], -2.f * acc0[m][3][j])),
                fminf(fminf(-2.f * acc1[m][0][j], -2.f * acc1[m][1][j]),
                      fminf(-2.f * acc1[m][2][j], -2.f * acc1[m][3][j])));
#pragma unroll
            for (int s = 1; s < 16; s <<= 1) v = fminf(v, __shfl_xor(v, s, 64));
            if (lr == 0)
                atomicMin(&sMinU[wr * 64 + m * 16 + lg * 4 + j], fmap(v));
        }
    }
    __syncthreads();
    if (t < 256) {
        unsigned g = rowminU[rowT + t];              // stale-ok cross-block running min
        unsigned tm = sMinU[t];
        sThr[t] = funmap(tm < g ? tm : g) + MARGIN;  // superset-safe threshold
        atomicMin(&rowminU[rowT + t], tm);           // 1 global atomic per row per block
    }
    __syncthreads();

    // ---- candidate admission ----
#pragma unroll
    for (int m = 0; m < 4; m++) {
#pragma unroll
        for (int j = 0; j < 4; j++) {
            const int rl = wr * 64 + m * 16 + lg * 4 + j;
            const float thr = sThr[rl];
#pragma unroll
            for (int h = 0; h < 2; h++) {
#pragma unroll
                for (int nn = 0; nn < 4; nn++) {
                    float d = -2.f * (h ? acc1[m][nn][j] : acc0[m][nn][j]);
                    if (d <= thr) {
                        unsigned pos = atomicAdd(&candCnt[rowT + rl], 1u);
                        if (pos < CAP)
                            candIdx[(size_t)(rowT + rl) * CAP + pos] =
                                (unsigned)(codeT + wc * 128 + h * 64 + nn * 16 + lr);
                    }
                }
            }
        }
    }
#undef STAGE
#undef LDA
#undef LDB
#undef MFMAH
#undef BAR
#undef LGKM0
#undef VMC8
#undef CLMP
}

// ---- phase 2: exact rescore (one wave per row; 8 lane-groups score 8 cands in parallel)
// Per-row f64 loss partial is written into the row's OWN candIdx slot (first 8 bytes)
// AFTER all candidate reads -- no cross-block hazard; k_lossred reduces with 64 atomics.
__global__ __launch_bounds__(256) void k_rescore(const float* __restrict__ z,
                                                 const float* __restrict__ emb,
                                                 const unsigned* __restrict__ candCnt,
                                                 unsigned* __restrict__ candIdx,
                                                 float* __restrict__ out) {
    const int w = threadIdx.x >> 6, l = threadIdx.x & 63;
    const int row = blockIdx.x * 4 + w;
    const int g = l >> 3, q = l & 7;     // 8 groups x 8 lanes
    const float* zr = z + (size_t)row * DDIM;

    // old-layout chunk (dims l*8..+7) for s1 (bit-identical to prior rounds) + epilogue
    floatx4 za  = *(const floatx4*)(zr + l * 8);
    floatx4 zb4 = *(const floatx4*)(zr + l * 8 + 4);
    double s1 = 0.0;
#pragma unroll
    for (int j = 0; j < 4; j++) { s1 += (double)za[j] * za[j]; s1 += (double)zb4[j] * zb4[j]; }
#pragma unroll
    for (int s = 1; s < 64; s <<= 1) s1 += __shfl_xor(s1, s, 64);
    const float s1f = (float)s1;

    // scoring layout: lane owns dims q*64..+63 (same for all groups)
    floatx4 zq[16];
#pragma unroll
    for (int k = 0; k < 16; k++) zq[k] = *(const floatx4*)(zr + q * 64 + k * 4);

    auto score = [&](unsigned c) -> unsigned long long {
        const float* er = emb + (size_t)c * DDIM + q * 64;
        double dt = 0.0;
#pragma unroll
        for (int k = 0; k < 16; k++) {
            floatx4 e = *(const floatx4*)(er + k * 4);
            dt += (double)zq[k][0] * (double)e[0];
            dt += (double)zq[k][1] * (double)e[1];
            dt += (double)zq[k][2] * (double)e[2];
            dt += (double)zq[k][3] * (double)e[3];
        }
        dt += __shfl_xor(dt, 1, 64);      // 3-level reduce within 8-lane group
        dt += __shfl_xor(dt, 2, 64);
        dt += __shfl_xor(dt, 4, 64);
        float uf = (float)(2.0 * dt);     // matches fl32(2*M_k) (f64 dot exact to >>f32)
        float df = s1f - uf;              // matches fl32(s1 - 2M) (||e||^2 provably vanishes)
        return ((unsigned long long)fmap(df) << 32) | (unsigned long long)c;
    };

    unsigned cnt = candCnt[row];
    unsigned long long best = ~0ull;
    if (cnt <= CAP) {
        for (unsigned i = g; i < cnt; i += 8) {
            unsigned long long k = score(candIdx[(size_t)row * CAP + i]);
            best = k < best ? k : best;
        }
    } else {  // overflow fallback: exact brute force (deterministic, rare)
        for (unsigned c = g; c < KCODES; c += 8) {
            unsigned long long k = score(c);
            best = k < best ? k : best;
        }
    }
    // cross-group min of (ordered-df, idx) keys -> wave-wide reference argmin
#pragma unroll
    for (int s = 8; s < 64; s <<= 1) {
        unsigned long long o = __shfl_xor(best, s, 64);
        best = o < best ? o : best;
    }
    const unsigned idx = (unsigned)best;  // low 32 bits

    // outputs: quantized_st = z + (q - z) in f32 (exact ST replication), loss partial
    const float* er = emb + (size_t)idx * DDIM + l * 8;
    float* oq = out + 1 + (size_t)row * DDIM + l * 8;   // 4B-aligned only
    double lp = 0.0;
#pragma unroll
    for (int j = 0; j < 8; j++) {
        float zv = (j < 4) ? za[j] : zb4[j - 4];
        float qv = er[j];
        oq[j] = zv + (qv - zv);
        double d = (double)qv - (double)zv;
        lp += d * d;
    }
#pragma unroll
    for (int s = 1; s < 64; s <<= 1) lp += __shfl_xor(lp, s, 64);
    if (l == 0) {
        out[1 + 16777216 + row] = (float)idx;   // indices as f32 values
        // all candidate reads for this row happened above (wave-lockstep) -> safe
        ((double*)(candIdx + (size_t)row * CAP))[0] = lp;
    }
}

// ---- phase 2b: tree-reduce per-row losses (64 blocks, 64 atomics total) ----
__global__ __launch_bounds__(256) void k_lossred(const unsigned* __restrict__ candIdx,
                                                 double* __restrict__ lossAcc) {
    const int tid = blockIdx.x * 256 + threadIdx.x;   // 0..16383
    double s = ((const double*)(candIdx + (size_t)tid * CAP))[0]
             + ((const double*)(candIdx + (size_t)(tid + 16384) * CAP))[0];
#pragma unroll
    for (int sh = 1; sh < 64; sh <<= 1) s += __shfl_xor(s, sh, 64);
    __shared__ double partial[4];
    const int l = threadIdx.x & 63, w = threadIdx.x >> 6;
    if (l == 0) partial[w] = s;
    __syncthreads();
    if (threadIdx.x == 0)
        atomicAdd(lossAcc, partial[0] + partial[1] + partial[2] + partial[3]);
}

// ---- phase 3: finalize loss = 1.25 * mean ----
__global__ void k_final(const double* __restrict__ lossAcc, float* __restrict__ out) {
    if (threadIdx.x == 0 && blockIdx.x == 0)
        out[0] = (float)(1.25 * (*lossAcc) * (1.0 / 16777216.0));
}

extern "C" void kernel_launch(void* const* d_in, const int* in_sizes, int n_in,
                              void* d_out, int out_size, void* d_ws, size_t ws_size,
                              hipStream_t stream) {
    const float* z   = (const float*)d_in[0];
    const float* emb = (const float*)d_in[1];
    float* out = (float*)d_out;
    char* ws = (char*)d_ws;
    unsigned short* zbf = (unsigned short*)(ws + OFF_ZBF);
    unsigned short* ebf = (unsigned short*)(ws + OFF_EBF);
    unsigned* rmin = (unsigned*)(ws + OFF_RMIN);
    unsigned* ccnt = (unsigned*)(ws + OFF_CCNT);
    unsigned* cidx = (unsigned*)(ws + OFF_CIDX);
    double* loss = (double*)(ws + OFF_LOSS);

    k_convert<<<dim3(NROWS * DDIM / 2048), 256, 0, stream>>>(z, zbf, NROWS * DDIM);
    k_convert<<<dim3(KCODES * DDIM / 2048), 256, 0, stream>>>(emb, ebf, KCODES * DDIM);
    k_init<<<dim3(128), 256, 0, stream>>>(rmin, ccnt, loss);
    // grid.x = row tiles (fast-varying): consecutive blocks share the B(code) tile in L2,
    // and a row's code-tiles are time-staggered => running min tightens admissions.
    k_gemm<<<dim3(128, 32), 512, 0, stream>>>(zbf, ebf, rmin, ccnt, cidx);
    k_rescore<<<dim3(NROWS / 4), 256, 0, stream>>>(z, emb, ccnt, cidx, out);
    k_lossred<<<dim3(64), 256, 0, stream>>>(cidx, loss);
    k_final<<<dim3(1), 64, 0, stream>>>(loss, out);
}